// Round 19
// baseline (115.064 us; speedup 1.0000x reference)
//
#include <hip/hip_runtime.h>
#include <stdint.h>

#define BB 2
#define HH 16
#define LL 2048
#define DD 1024

typedef __bf16 b16x8 __attribute__((ext_vector_type(8)));
typedef float f32x4 __attribute__((ext_vector_type(4)));
typedef int i32x4 __attribute__((ext_vector_type(4)));

__device__ __forceinline__ short f2bf(float f) {
  unsigned u = __builtin_bit_cast(unsigned, f);
  return (short)((u + 0x7fffu + ((u >> 16) & 1u)) >> 16);
}

// native bf16 convert
__device__ __forceinline__ short bfc(float f) {
  return __builtin_bit_cast(short, static_cast<__bf16>(f));
}

// packed f32x2 -> bf16x2 (no builtin on gfx950; inline asm)
__device__ __forceinline__ int cvtpk(float lo, float hi) {
  int r;
  asm("v_cvt_pk_bf16_f32 %0, %1, %2" : "=v"(r) : "v"(lo), "v"(hi));
  return r;
}

__device__ __forceinline__ void gl_lds16(const void* gp, void* lp) {
  __builtin_amdgcn_global_load_lds(
      (const __attribute__((address_space(1))) void*)gp,
      (__attribute__((address_space(3))) void*)lp, 16, 0, 0);
}

// ---------------- prep: X f32->bf16 (z=4) + W transpose (z=0..3) ----------
__global__ __launch_bounds__(256) void prep(const float* __restrict__ X,
                                            short* __restrict__ Xb,
                                            const float* __restrict__ W0,
                                            const float* __restrict__ W1,
                                            const float* __restrict__ W2,
                                            const float* __restrict__ W3,
                                            short* __restrict__ Wt) {
  if (blockIdx.z == 4) {
    int base = (blockIdx.y * 32 + blockIdx.x) * 1024 + threadIdx.x;
#pragma unroll
    for (int k = 0; k < 4; ++k) {
      int i = base + k * 256;
      float4 v = ((const float4*)X)[i];
      short4 o;
      o.x = f2bf(v.x); o.y = f2bf(v.y); o.z = f2bf(v.z); o.w = f2bf(v.w);
      ((short4*)Xb)[i] = o;
    }
    return;
  }
  __shared__ float t[32][33];
  const float* W = blockIdx.z == 0 ? W0 : blockIdx.z == 1 ? W1
                 : blockIdx.z == 2 ? W2 : W3;
  short* dst = Wt + (size_t)blockIdx.z * DD * DD;
  int tx = threadIdx.x & 31, ty0 = threadIdx.x >> 5;
  int nb = blockIdx.x * 32, kb = blockIdx.y * 32;
#pragma unroll
  for (int i = 0; i < 4; ++i)
    t[ty0 + i * 8][tx] = W[(size_t)(kb + ty0 + i * 8) * DD + nb + tx];
  __syncthreads();
#pragma unroll
  for (int i = 0; i < 4; ++i)
    dst[(size_t)(nb + ty0 + i * 8) * DD + kb + tx] = f2bf(t[tx][ty0 + i * 8]);
}

// ---------------- fused QKV GEMM: [4096,1024] @ Wt -> Q,K,Vt ---------------
// XCD-chunked swizzle: 768 = 8 x 96. BK=64: 16 K-iterations (half the
// barriers), attn-proven [rows][64] LDS pattern — pre-swizzled gl_lds source
// (c8^r8)*8 + conflict-free b128 reads row*128 ^ ((lrow&7)<<4).
__global__ __launch_bounds__(256) void qkv_gemm(const short* __restrict__ Xb,
                                                const short* __restrict__ Wall,
                                                const float* __restrict__ bQ,
                                                const float* __restrict__ bK,
                                                const float* __restrict__ bV,
                                                short* __restrict__ Qo,
                                                short* __restrict__ Ko,
                                                short* __restrict__ Vto) {
  __shared__ __align__(16) short As[128 * 64];
  __shared__ __align__(16) short Bs[128 * 64];

  const int tid = threadIdx.x;
  const int lane = tid & 63;
  const int wid = tid >> 6;
  const int orig = blockIdx.x + 24 * blockIdx.y;
  const int nid = (orig & 7) * 96 + (orig >> 3);
  const int m0 = (nid & 31) * 128;
  const int ng = (nid >> 5) * 128;
  const int sel = ng >> 10;
  const int n0 = ng & 1023;
  const short* W = Wall + (size_t)sel * DD * DD;

  const int wrow = wid >> 1, wcol = wid & 1;
  const int lrow = lane & 15;
  const int hi = lane >> 4;
  const int hi16b = hi * 16;
  const int r8 = lane >> 3;
  const int c8 = lane & 7;
  const int swz8 = (c8 ^ r8) * 8;  // pre-swizzled global source (elems)

  // hoisted conflict-free read byte-offsets (sw = (lrow&7)<<4 uniform)
  const int sw = (lrow & 7) << 4;
  int offa[4][2], offb[4][2];
#pragma unroll
  for (int i = 0; i < 4; ++i)
#pragma unroll
    for (int ks = 0; ks < 2; ++ks) {
      offa[i][ks] = (wrow * 64 + i * 16 + lrow) * 128 + ((ks * 64 + hi16b) ^ sw);
      offb[i][ks] = (wcol * 64 + i * 16 + lrow) * 128 + ((ks * 64 + hi16b) ^ sw);
    }

  f32x4 z4 = {0.f, 0.f, 0.f, 0.f};
  f32x4 acc[4][4];
#pragma unroll
  for (int i = 0; i < 4; ++i)
#pragma unroll
    for (int j = 0; j < 4; ++j) acc[i][j] = z4;

  for (int kt = 0; kt < DD; kt += 64) {
#pragma unroll
    for (int i = 0; i < 4; ++i) {
      int c = wid * 4 + i;  // 16 chunks of 8 rows
      gl_lds16(Xb + (size_t)(m0 + c * 8 + r8) * DD + kt + swz8, As + c * 512);
      gl_lds16(W + (size_t)(n0 + c * 8 + r8) * DD + kt + swz8, Bs + c * 512);
    }
    __syncthreads();
#pragma unroll
    for (int ks = 0; ks < 2; ++ks) {
      b16x8 a[4], b[4];
#pragma unroll
      for (int i = 0; i < 4; ++i)
        a[i] = *(const b16x8*)((const char*)As + offa[i][ks]);
#pragma unroll
      for (int j = 0; j < 4; ++j)
        b[j] = *(const b16x8*)((const char*)Bs + offb[j][ks]);
#pragma unroll
      for (int i = 0; i < 4; ++i)
#pragma unroll
        for (int j = 0; j < 4; ++j)
          acc[i][j] = __builtin_amdgcn_mfma_f32_16x16x32_bf16(a[i], b[j], acc[i][j], 0, 0, 0);
    }
    __syncthreads();
  }

  const float* bias = sel == 0 ? bQ : sel == 1 ? bK : bV;
  float bv[4];
#pragma unroll
  for (int j = 0; j < 4; ++j) bv[j] = bias[n0 + wcol * 64 + j * 16 + lrow];

  const int rbase = hi * 4;
  if (sel == 2) {
    // V: write transposed (B,H,DK,L) with keys PERMUTED within each 64-tile.
#pragma unroll
    for (int i = 0; i < 4; ++i) {
      int gm = m0 + wrow * 64 + i * 16 + rbase;
      int bb = gm >> 11, lb = gm & 2047;
      int x = lb & 63;
      int kf = x >> 4;
      int lbp = (lb & ~63) | ((kf >> 1) << 5) | (((x >> 2) & 3) << 3) | ((kf & 1) << 2);
#pragma unroll
      for (int j = 0; j < 4; ++j) {
        int gn = n0 + wcol * 64 + j * 16 + lrow;
        int h = gn >> 6, dk = gn & 63;
        short4 pk;
        pk.x = bfc(acc[i][j][0] + bv[j]);
        pk.y = bfc(acc[i][j][1] + bv[j]);
        pk.z = bfc(acc[i][j][2] + bv[j]);
        pk.w = bfc(acc[i][j][3] + bv[j]);
        *(short4*)(Vto + ((size_t)((bb * HH + h) * 64 + dk)) * LL + lbp) = pk;
      }
    }
  } else {
    short* dst = sel == 0 ? Qo : Ko;
    // Q: fold 1/sqrt(64) AND log2(e) so softmax runs in exp2 domain.
    float sc = sel == 0 ? 0.18033688011112042f : 1.0f;
#pragma unroll
    for (int i = 0; i < 4; ++i) {
      int gm = m0 + wrow * 64 + i * 16 + rbase;
#pragma unroll
      for (int j = 0; j < 4; ++j) {
        int gn = n0 + wcol * 64 + j * 16 + lrow;
        int h = gn >> 6, dk = gn & 63;
#pragma unroll
        for (int r = 0; r < 4; ++r) {
          int m = gm + r;
          int bb = m >> 11, lq = m & 2047;
          dst[((size_t)(bb * HH + h) * LL + lq) * 64 + dk] =
              bfc((acc[i][j][r] + bv[j]) * sc);
        }
      }
    }
  }
}

// ---------------- flash attention (swapped-operand, KVBLK=128) -------------
// grid (16, 32): 128 q-rows/block, 4 waves x 32 rows, XCD-chunked swizzle.
// 2-slot LDS ring (64KB), gl_lds prefetch 1 tile ahead, vmcnt(0)+raw
// s_barrier per 128-key tile. V keys pre-permuted per 64-sub -> PV read is
// a conflict-free b128. S^T = mfma(K,Q) with C-init = -m.
__global__ __launch_bounds__(256, 2) void attn(const short* __restrict__ Qg,
                                               const short* __restrict__ Kg,
                                               const short* __restrict__ Vt,
                                               short* __restrict__ Og) {
  __shared__ __align__(16) short Ks[2][128 * 64];     // [key][d], swizzled
  __shared__ __align__(16) short Vs[2][2][64 * 64];   // [sub][d][perm-key]

  const int tid = threadIdx.x;
  const int lane = tid & 63;
  const int wid = tid >> 6;

  // bijective XCD-chunked swizzle: 512 = 8 x 64 -> 4 bh per XCD (2MB KV/L2)
  const int orig = blockIdx.x + 16 * blockIdx.y;
  const int nid = (orig & 7) * 64 + (orig >> 3);
  const int bh = nid >> 4;
  const int q0 = (nid & 15) * 128 + wid * 32;

  const short* Qb = Qg + (size_t)bh * LL * 64;
  const short* Kb = Kg + (size_t)bh * LL * 64;
  const short* Vb = Vt + (size_t)bh * 64 * LL;

  const int lrow = lane & 15;
  const int hi = lane >> 4;     // 0..3
  const int hi8 = hi * 8;       // shorts
  const int hi16b = hi * 16;    // bytes
  const int r8 = lane >> 3;     // staging row within 8-row chunk
  const int c8 = lane & 7;
  const int swz8 = (c8 ^ r8) * 8;  // pre-swizzled global source offset (elems)

  // Q fragment: B-operand of swapped QK (col=q=lrow, k=hi*8+j)
  b16x8 qf[2][2];
#pragma unroll
  for (int f = 0; f < 2; ++f)
#pragma unroll
    for (int ks = 0; ks < 2; ++ks)
      qf[f][ks] = *(const b16x8*)(Qb + (size_t)(q0 + f * 16 + lrow) * 64 + ks * 32 + hi8);

  f32x4 z4 = {0.f, 0.f, 0.f, 0.f};
  f32x4 accO[2][4];   // accO[f][db]: O^T[d=db*16+hi*4+r][q=f*16+lrow]
  float nm[2], l_i[2];  // nm = -m (running); l_i LANE-PARTIAL across hi
#pragma unroll
  for (int f = 0; f < 2; ++f) {
#pragma unroll
    for (int d = 0; d < 4; ++d) accO[f][d] = z4;
    nm[f] = 0.f; l_i[f] = 0.f;  // m starts at 0: exp2(S) bounded by defer-max
  }

  // hoisted LDS read byte-offsets (K uses a=0..7; V subs use a=0..3)
  int offs[8][2];
#pragma unroll
  for (int a = 0; a < 8; ++a) {
    int row = a * 16 + lrow;
    int sw = (row & 7) << 4;
#pragma unroll
    for (int ks = 0; ks < 2; ++ks)
      offs[a][ks] = row * 128 + ((ks * 64 + hi16b) ^ sw);
  }

  // stage 128-key tile kt_ into slot buf_ (8 gl_lds per wave: 4 K + 4 V)
  auto stage = [&](int kt_, int buf_) {
#pragma unroll
    for (int i = 0; i < 4; ++i) {
      int c = wid * 4 + i;  // 16 K chunks of 8 rows
      gl_lds16(Kb + (size_t)(kt_ * 128 + c * 8 + r8) * 64 + swz8, &Ks[buf_][c * 512]);
    }
#pragma unroll
    for (int s = 0; s < 2; ++s)
#pragma unroll
      for (int i = 0; i < 2; ++i) {
        int c = wid * 2 + i;  // 8 V chunks of 8 d-rows per sub
        gl_lds16(Vb + (size_t)(c * 8 + r8) * LL + kt_ * 128 + s * 64 + swz8,
                 &Vs[buf_][s][c * 512]);
      }
  };

  // prologue
  stage(0, 0);
  asm volatile("s_waitcnt vmcnt(0)" ::: "memory");
  __builtin_amdgcn_s_barrier();

  int buf = 0;
  for (int kt = 0; kt < LL / 128; ++kt) {
    if (kt + 1 < LL / 128) stage(kt + 1, buf ^ 1);

    const char* ksb = (const char*)&Ks[buf][0];

    // S^T - m = mfma(K, Q) with C init = -m; kf=0..7 covers 128 keys
    f32x4 sacc[2][8];
#pragma unroll
    for (int f = 0; f < 2; ++f) {
      f32x4 nm4 = {nm[f], nm[f], nm[f], nm[f]};
#pragma unroll
      for (int kf = 0; kf < 8; ++kf) sacc[f][kf] = nm4;
    }

    __builtin_amdgcn_s_setprio(1);
#pragma unroll
    for (int kf = 0; kf < 8; ++kf) {
#pragma unroll
      for (int ks = 0; ks < 2; ++ks) {
        b16x8 kfr = *(const b16x8*)(ksb + offs[kf][ks]);
#pragma unroll
        for (int f = 0; f < 2; ++f)
          sacc[f][kf] =
              __builtin_amdgcn_mfma_f32_16x16x32_bf16(kfr, qf[f][ks], sacc[f][kf], 0, 0, 0);
      }
    }
    __builtin_amdgcn_s_setprio(0);

    // ---- defer-max online softmax: sacc already holds S - m_old ----
    float lm[2];
#pragma unroll
    for (int f = 0; f < 2; ++f) {
      float mx = fmaxf(fmaxf(sacc[f][0][0], sacc[f][0][1]),
                       fmaxf(sacc[f][0][2], sacc[f][0][3]));
#pragma unroll
      for (int kf = 1; kf < 8; ++kf)
        mx = fmaxf(mx, fmaxf(fmaxf(sacc[f][kf][0], sacc[f][kf][1]),
                             fmaxf(sacc[f][kf][2], sacc[f][kf][3])));
      lm[f] = mx;
    }
    float w = fmaxf(lm[0], lm[1]);

    if (!__all(w <= 8.0f)) {
      // rare path: reduce delta across the 4 hi-lanes, rescale, shift sacc
#pragma unroll
      for (int f = 0; f < 2; ++f) {
        float mx = lm[f];
        mx = fmaxf(mx, __shfl_xor(mx, 16));
        mx = fmaxf(mx, __shfl_xor(mx, 32));
        float d = fmaxf(mx, 0.f);       // m_new = m_old + d
        float corr = __builtin_amdgcn_exp2f(-d);
        l_i[f] *= corr;
        nm[f] -= d;
#pragma unroll
        for (int db = 0; db < 4; ++db) accO[f][db] *= corr;
#pragma unroll
        for (int kf = 0; kf < 8; ++kf) sacc[f][kf] -= d;
      }
    }

    // P = exp2(sacc) packed via cvt_pk; slot c = kf>>1 (4 slots of 32 keys)
    b16x8 pfr[2][4];
#pragma unroll
    for (int f = 0; f < 2; ++f) {
      float ps = 0.f;
#pragma unroll
      for (int c = 0; c < 4; ++c) {
        float e0 = __builtin_amdgcn_exp2f(sacc[f][2 * c][0]);
        float e1 = __builtin_amdgcn_exp2f(sacc[f][2 * c][1]);
        float e2 = __builtin_amdgcn_exp2f(sacc[f][2 * c][2]);
        float e3 = __builtin_amdgcn_exp2f(sacc[f][2 * c][3]);
        float e4 = __builtin_amdgcn_exp2f(sacc[f][2 * c + 1][0]);
        float e5 = __builtin_amdgcn_exp2f(sacc[f][2 * c + 1][1]);
        float e6 = __builtin_amdgcn_exp2f(sacc[f][2 * c + 1][2]);
        float e7 = __builtin_amdgcn_exp2f(sacc[f][2 * c + 1][3]);
        ps += ((e0 + e1) + (e2 + e3)) + ((e4 + e5) + (e6 + e7));
        i32x4 pt;
        pt[0] = cvtpk(e0, e1);
        pt[1] = cvtpk(e2, e3);
        pt[2] = cvtpk(e4, e5);
        pt[3] = cvtpk(e6, e7);
        pfr[f][c] = __builtin_bit_cast(b16x8, pt);
      }
      l_i[f] += ps;
    }

    // V fragments: slot = sub*2 + ks; conflict-free b128 per sub
    b16x8 vfr[4][4];
#pragma unroll
    for (int db = 0; db < 4; ++db)
#pragma unroll
      for (int sl = 0; sl < 4; ++sl) {
        const char* vsb = (const char*)&Vs[buf][sl >> 1][0];
        vfr[db][sl] = *(const b16x8*)(vsb + offs[db][sl & 1]);
      }

    // O^T += mfma(V, P) over 4 k-slots
    __builtin_amdgcn_s_setprio(1);
#pragma unroll
    for (int f = 0; f < 2; ++f)
#pragma unroll
      for (int db = 0; db < 4; ++db)
#pragma unroll
        for (int sl = 0; sl < 4; ++sl)
          accO[f][db] = __builtin_amdgcn_mfma_f32_16x16x32_bf16(vfr[db][sl], pfr[f][sl],
                                                                accO[f][db], 0, 0, 0);
    __builtin_amdgcn_s_setprio(0);

    // next tile resident before flip
    asm volatile("s_waitcnt vmcnt(0)" ::: "memory");
    __builtin_amdgcn_s_barrier();
    buf ^= 1;
  }

  // epilogue: reduce lane-partial l across hi, O /= l, packed short4 stores
  const int bb = bh >> 4, h = bh & 15;
#pragma unroll
  for (int f = 0; f < 2; ++f) {
    float l = l_i[f];
    l += __shfl_xor(l, 16);
    l += __shfl_xor(l, 32);
    float rl = 1.0f / l;
    int q = q0 + f * 16 + lrow;
#pragma unroll
    for (int db = 0; db < 4; ++db) {
      short4 pk;
      pk.x = bfc(accO[f][db][0] * rl);
      pk.y = bfc(accO[f][db][1] * rl);
      pk.z = bfc(accO[f][db][2] * rl);
      pk.w = bfc(accO[f][db][3] * rl);
      *(short4*)(Og + (size_t)(bb * LL + q) * DD + h * 64 + db * 16 + hi * 4) = pk;
    }
  }
}

// ---------------- output GEMM: attn[4096,1024] @ WOt + bO -> f32 ----------
// 64x128 tile, BK=64 (16 iterations), attn-proven swizzled LDS pattern.
__global__ __launch_bounds__(256) void out_gemm(const short* __restrict__ Ab,
                                                const short* __restrict__ Wt,
                                                const float* __restrict__ bO,
                                                float* __restrict__ Out) {
  __shared__ __align__(16) short As[64 * 64];
  __shared__ __align__(16) short Bs[128 * 64];

  const int tid = threadIdx.x;
  const int lane = tid & 63;
  const int wid = tid >> 6;
  const int orig = blockIdx.x + 8 * blockIdx.y;   // grid (8, 64)
  const int nid = (orig & 7) * 64 + (orig >> 3);  // bijective: 512 = 8*64
  const int n0 = (nid >> 6) * 128;
  const int m0 = (nid & 63) * 64;

  const int wrow = wid >> 1, wcol = wid & 1;  // wave tile: 32 rows x 64 cols
  const int lrow = lane & 15;
  const int hi = lane >> 4;
  const int hi16b = hi * 16;
  const int r8 = lane >> 3;
  const int c8 = lane & 7;
  const int swz8 = (c8 ^ r8) * 8;

  const int sw = (lrow & 7) << 4;
  int offa[2][2], offb[4][2];
#pragma unroll
  for (int ks = 0; ks < 2; ++ks) {
#pragma unroll
    for (int i = 0; i < 2; ++i)
      offa[i][ks] = (wrow * 32 + i * 16 + lrow) * 128 + ((ks * 64 + hi16b) ^ sw);
#pragma unroll
    for (int j = 0; j < 4; ++j)
      offb[j][ks] = (wcol * 64 + j * 16 + lrow) * 128 + ((ks * 64 + hi16b) ^ sw);
  }

  f32x4 z4 = {0.f, 0.f, 0.f, 0.f};
  f32x4 acc[2][4];
#pragma unroll
  for (int i = 0; i < 2; ++i)
#pragma unroll
    for (int j = 0; j < 4; ++j) acc[i][j] = z4;

  for (int kt = 0; kt < DD; kt += 64) {
    // A: 64 rows = 8 chunks of 8 rows (2/wave). B: 128 rows = 16 (4/wave).
#pragma unroll
    for (int i = 0; i < 2; ++i) {
      int c = wid * 2 + i;
      gl_lds16(Ab + (size_t)(m0 + c * 8 + r8) * DD + kt + swz8, As + c * 512);
    }
#pragma unroll
    for (int i = 0; i < 4; ++i) {
      int c = wid * 4 + i;
      gl_lds16(Wt + (size_t)(n0 + c * 8 + r8) * DD + kt + swz8, Bs + c * 512);
    }
    __syncthreads();
#pragma unroll
    for (int ks = 0; ks < 2; ++ks) {
      b16x8 a[2], b[4];
#pragma unroll
      for (int i = 0; i < 2; ++i)
        a[i] = *(const b16x8*)((const char*)As + offa[i][ks]);
#pragma unroll
      for (int j = 0; j < 4; ++j)
        b[j] = *(const b16x8*)((const char*)Bs + offb[j][ks]);
#pragma unroll
      for (int i = 0; i < 2; ++i)
#pragma unroll
        for (int j = 0; j < 4; ++j)
          acc[i][j] = __builtin_amdgcn_mfma_f32_16x16x32_bf16(a[i], b[j], acc[i][j], 0, 0, 0);
    }
    __syncthreads();
  }

  float bv[4];
#pragma unroll
  for (int j = 0; j < 4; ++j) bv[j] = bO[n0 + wcol * 64 + j * 16 + lrow];

  const int rbase = hi * 4;
#pragma unroll
  for (int i = 0; i < 2; ++i) {
    int gm = m0 + wrow * 32 + i * 16 + rbase;
#pragma unroll
    for (int j = 0; j < 4; ++j) {
      int gn = n0 + wcol * 64 + j * 16 + lrow;
#pragma unroll
      for (int r = 0; r < 4; ++r)
        Out[(size_t)(gm + r) * DD + gn] = acc[i][j][r] + bv[j];
    }
  }
}

extern "C" void kernel_launch(void* const* d_in, const int* in_sizes, int n_in,
                              void* d_out, int out_size, void* d_ws, size_t ws_size,
                              hipStream_t stream) {
  const float* X = (const float*)d_in[0];
  const float* WQ = (const float*)d_in[1];
  const float* bQ = (const float*)d_in[2];
  const float* WK = (const float*)d_in[3];
  const float* bK = (const float*)d_in[4];
  const float* WV = (const float*)d_in[5];
  const float* bV = (const float*)d_in[6];
  const float* WO = (const float*)d_in[7];
  const float* bO = (const float*)d_in[8];
  float* Out = (float*)d_out;

  // workspace layout (shorts): Xb 4M | Wt 4x1M | Q 4M | K 4M | Vt 4M | At 4M
  if (ws_size < (size_t)24 * 1024 * 1024 * 2) return;
  short* ws = (short*)d_ws;
  short* Xb = ws;
  short* Wt = Xb + (size_t)4096 * 1024;
  short* Qb = Wt + (size_t)4 * 1024 * 1024;
  short* Kb = Qb + (size_t)4096 * 1024;
  short* Vtb = Kb + (size_t)4096 * 1024;
  short* At = Vtb + (size_t)4096 * 1024;

  hipLaunchKernelGGL(prep, dim3(32, 32, 5), dim3(256), 0, stream, X, Xb, WQ, WK, WV, WO, Wt);
  hipLaunchKernelGGL(qkv_gemm, dim3(24, 32), dim3(256), 0, stream, Xb, Wt, bQ, bK, bV,
                     Qb, Kb, Vtb);
  hipLaunchKernelGGL(attn, dim3(16, 32), dim3(256), 0, stream, Qb, Kb, Vtb, At);
  hipLaunchKernelGGL(out_gemm, dim3(8, 64), dim3(256), 0, stream, At,
                     Wt + (size_t)3 * 1024 * 1024, bO, Out);
}

// Round 20
// 104.054 us; speedup vs baseline: 1.1058x; 1.1058x over previous
//
#include <hip/hip_runtime.h>
#include <stdint.h>

#define BB 2
#define HH 16
#define LL 2048
#define DD 1024

typedef __bf16 b16x8 __attribute__((ext_vector_type(8)));
typedef float f32x4 __attribute__((ext_vector_type(4)));
typedef int i32x4 __attribute__((ext_vector_type(4)));

__device__ __forceinline__ short f2bf(float f) {
  unsigned u = __builtin_bit_cast(unsigned, f);
  return (short)((u + 0x7fffu + ((u >> 16) & 1u)) >> 16);
}

// native bf16 convert
__device__ __forceinline__ short bfc(float f) {
  return __builtin_bit_cast(short, static_cast<__bf16>(f));
}

// packed f32x2 -> bf16x2 (no builtin on gfx950; inline asm)
__device__ __forceinline__ int cvtpk(float lo, float hi) {
  int r;
  asm("v_cvt_pk_bf16_f32 %0, %1, %2" : "=v"(r) : "v"(lo), "v"(hi));
  return r;
}

__device__ __forceinline__ void gl_lds16(const void* gp, void* lp) {
  __builtin_amdgcn_global_load_lds(
      (const __attribute__((address_space(1))) void*)gp,
      (__attribute__((address_space(3))) void*)lp, 16, 0, 0);
}

// ---------------- prep: X f32->bf16 (z=4) + W transpose (z=0..3) ----------
__global__ __launch_bounds__(256) void prep(const float* __restrict__ X,
                                            short* __restrict__ Xb,
                                            const float* __restrict__ W0,
                                            const float* __restrict__ W1,
                                            const float* __restrict__ W2,
                                            const float* __restrict__ W3,
                                            short* __restrict__ Wt) {
  if (blockIdx.z == 4) {
    int base = (blockIdx.y * 32 + blockIdx.x) * 1024 + threadIdx.x;
#pragma unroll
    for (int k = 0; k < 4; ++k) {
      int i = base + k * 256;
      float4 v = ((const float4*)X)[i];
      short4 o;
      o.x = f2bf(v.x); o.y = f2bf(v.y); o.z = f2bf(v.z); o.w = f2bf(v.w);
      ((short4*)Xb)[i] = o;
    }
    return;
  }
  __shared__ float t[32][33];
  const float* W = blockIdx.z == 0 ? W0 : blockIdx.z == 1 ? W1
                 : blockIdx.z == 2 ? W2 : W3;
  short* dst = Wt + (size_t)blockIdx.z * DD * DD;
  int tx = threadIdx.x & 31, ty0 = threadIdx.x >> 5;
  int nb = blockIdx.x * 32, kb = blockIdx.y * 32;
#pragma unroll
  for (int i = 0; i < 4; ++i)
    t[ty0 + i * 8][tx] = W[(size_t)(kb + ty0 + i * 8) * DD + nb + tx];
  __syncthreads();
#pragma unroll
  for (int i = 0; i < 4; ++i)
    dst[(size_t)(nb + ty0 + i * 8) * DD + kb + tx] = f2bf(t[tx][ty0 + i * 8]);
}

// ---------------- fused QKV GEMM: [4096,1024] @ Wt -> Q,K,Vt ---------------
// XCD-chunked swizzle: 768 = 8 x 96; T2 slot-swizzle on As/Bs.
__global__ __launch_bounds__(256) void qkv_gemm(const short* __restrict__ Xb,
                                                const short* __restrict__ Wall,
                                                const float* __restrict__ bQ,
                                                const float* __restrict__ bK,
                                                const float* __restrict__ bV,
                                                short* __restrict__ Qo,
                                                short* __restrict__ Ko,
                                                short* __restrict__ Vto) {
  __shared__ __align__(16) short As[128 * 32];
  __shared__ __align__(16) short Bs[128 * 32];

  const int tid = threadIdx.x;
  const int lane = tid & 63;
  const int wid = tid >> 6;
  const int orig = blockIdx.x + 24 * blockIdx.y;
  const int nid = (orig & 7) * 96 + (orig >> 3);
  const int m0 = (nid & 31) * 128;
  const int ng = (nid >> 5) * 128;
  const int sel = ng >> 10;
  const int n0 = ng & 1023;
  const short* W = Wall + (size_t)sel * DD * DD;

  const int wrow = wid >> 1, wcol = wid & 1;
  const int lrow = lane & 15;
  const int hi = lane >> 4;
  const int sl8 = (hi ^ ((lrow >> 1) & 3)) * 8;  // swizzled read slot
  const int srow = lane >> 2;
  const int scol = ((lane & 3) ^ ((lane >> 3) & 3)) * 8;  // pre-swizzled src

  f32x4 z4 = {0.f, 0.f, 0.f, 0.f};
  f32x4 acc[4][4];
#pragma unroll
  for (int i = 0; i < 4; ++i)
#pragma unroll
    for (int j = 0; j < 4; ++j) acc[i][j] = z4;

  for (int kt = 0; kt < DD; kt += 32) {
#pragma unroll
    for (int i = 0; i < 2; ++i) {
      int c = wid * 2 + i;
      gl_lds16(Xb + (size_t)(m0 + c * 16 + srow) * DD + kt + scol, As + c * 512);
      gl_lds16(W + (size_t)(n0 + c * 16 + srow) * DD + kt + scol, Bs + c * 512);
    }
    __syncthreads();
    b16x8 a[4], b[4];
#pragma unroll
    for (int i = 0; i < 4; ++i)
      a[i] = *(const b16x8*)(As + (wrow * 64 + i * 16 + lrow) * 32 + sl8);
#pragma unroll
    for (int j = 0; j < 4; ++j)
      b[j] = *(const b16x8*)(Bs + (wcol * 64 + j * 16 + lrow) * 32 + sl8);
#pragma unroll
    for (int i = 0; i < 4; ++i)
#pragma unroll
      for (int j = 0; j < 4; ++j)
        acc[i][j] = __builtin_amdgcn_mfma_f32_16x16x32_bf16(a[i], b[j], acc[i][j], 0, 0, 0);
    __syncthreads();
  }

  const float* bias = sel == 0 ? bQ : sel == 1 ? bK : bV;
  float bv[4];
#pragma unroll
  for (int j = 0; j < 4; ++j) bv[j] = bias[n0 + wcol * 64 + j * 16 + lrow];

  const int rbase = hi * 4;
  if (sel == 2) {
    // V: write transposed (B,H,DK,L) with keys PERMUTED within each 64-tile.
#pragma unroll
    for (int i = 0; i < 4; ++i) {
      int gm = m0 + wrow * 64 + i * 16 + rbase;
      int bb = gm >> 11, lb = gm & 2047;
      int x = lb & 63;
      int kf = x >> 4;
      int lbp = (lb & ~63) | ((kf >> 1) << 5) | (((x >> 2) & 3) << 3) | ((kf & 1) << 2);
#pragma unroll
      for (int j = 0; j < 4; ++j) {
        int gn = n0 + wcol * 64 + j * 16 + lrow;
        int h = gn >> 6, dk = gn & 63;
        short4 pk;
        pk.x = bfc(acc[i][j][0] + bv[j]);
        pk.y = bfc(acc[i][j][1] + bv[j]);
        pk.z = bfc(acc[i][j][2] + bv[j]);
        pk.w = bfc(acc[i][j][3] + bv[j]);
        *(short4*)(Vto + ((size_t)((bb * HH + h) * 64 + dk)) * LL + lbp) = pk;
      }
    }
  } else {
    short* dst = sel == 0 ? Qo : Ko;
    // Q: fold 1/sqrt(64) AND log2(e) so softmax runs in exp2 domain.
    float sc = sel == 0 ? 0.18033688011112042f : 1.0f;
#pragma unroll
    for (int i = 0; i < 4; ++i) {
      int gm = m0 + wrow * 64 + i * 16 + rbase;
#pragma unroll
      for (int j = 0; j < 4; ++j) {
        int gn = n0 + wcol * 64 + j * 16 + lrow;
        int h = gn >> 6, dk = gn & 63;
#pragma unroll
        for (int r = 0; r < 4; ++r) {
          int m = gm + r;
          int bb = m >> 11, lq = m & 2047;
          dst[((size_t)(bb * HH + h) * LL + lq) * 64 + dk] =
              bfc((acc[i][j][r] + bv[j]) * sc);
        }
      }
    }
  }
}

// ---------------- flash attention (swapped-operand, KVBLK=128) -------------
// grid (16, 32): 128 q-rows/block, 4 waves x 32 rows, XCD-chunked swizzle.
// KVBLK=128 halves per-tile fixed costs (16 barriers/drains instead of 32).
// 2-slot LDS ring (64KB, 2 blocks/CU), gl_lds prefetch 1 tile ahead,
// vmcnt(0)+raw s_barrier per tile. V keys pre-permuted per 64-sub -> PV
// read is a conflict-free b128. S^T = mfma(K,Q) with C-init = -m.
__global__ __launch_bounds__(256, 2) void attn(const short* __restrict__ Qg,
                                               const short* __restrict__ Kg,
                                               const short* __restrict__ Vt,
                                               short* __restrict__ Og) {
  __shared__ __align__(16) short Ks[2][128 * 64];     // [key][d], swizzled
  __shared__ __align__(16) short Vs[2][2][64 * 64];   // [sub][d][perm-key]

  const int tid = threadIdx.x;
  const int lane = tid & 63;
  const int wid = tid >> 6;

  // bijective XCD-chunked swizzle: 512 = 8 x 64 -> 4 bh per XCD (2MB KV/L2)
  const int orig = blockIdx.x + 16 * blockIdx.y;
  const int nid = (orig & 7) * 64 + (orig >> 3);
  const int bh = nid >> 4;
  const int q0 = (nid & 15) * 128 + wid * 32;

  const short* Qb = Qg + (size_t)bh * LL * 64;
  const short* Kb = Kg + (size_t)bh * LL * 64;
  const short* Vb = Vt + (size_t)bh * 64 * LL;

  const int lrow = lane & 15;
  const int hi = lane >> 4;     // 0..3
  const int hi8 = hi * 8;       // shorts
  const int hi16b = hi * 16;    // bytes
  const int r8 = lane >> 3;     // staging row within 8-row chunk
  const int c8 = lane & 7;
  const int swz8 = (c8 ^ r8) * 8;  // pre-swizzled global source offset (elems)

  // Q fragment: B-operand of swapped QK (col=q=lrow, k=hi*8+j)
  b16x8 qf[2][2];
#pragma unroll
  for (int f = 0; f < 2; ++f)
#pragma unroll
    for (int ks = 0; ks < 2; ++ks)
      qf[f][ks] = *(const b16x8*)(Qb + (size_t)(q0 + f * 16 + lrow) * 64 + ks * 32 + hi8);

  f32x4 z4 = {0.f, 0.f, 0.f, 0.f};
  f32x4 accO[2][4];   // accO[f][db]: O^T[d=db*16+hi*4+r][q=f*16+lrow]
  float nm[2], l_i[2];  // nm = -m (running); l_i LANE-PARTIAL across hi
#pragma unroll
  for (int f = 0; f < 2; ++f) {
#pragma unroll
    for (int d = 0; d < 4; ++d) accO[f][d] = z4;
    nm[f] = 0.f; l_i[f] = 0.f;  // m starts at 0: exp2(S) bounded by defer-max
  }

  // hoisted LDS read byte-offsets (K uses a=0..7; V subs use a=0..3)
  int offs[8][2];
#pragma unroll
  for (int a = 0; a < 8; ++a) {
    int row = a * 16 + lrow;
    int sw = (row & 7) << 4;
#pragma unroll
    for (int ks = 0; ks < 2; ++ks)
      offs[a][ks] = row * 128 + ((ks * 64 + hi16b) ^ sw);
  }

  // stage 128-key tile kt_ into slot buf_ (8 gl_lds per wave: 4 K + 4 V)
  auto stage = [&](int kt_, int buf_) {
#pragma unroll
    for (int i = 0; i < 4; ++i) {
      int c = wid * 4 + i;  // 16 K chunks of 8 rows
      gl_lds16(Kb + (size_t)(kt_ * 128 + c * 8 + r8) * 64 + swz8, &Ks[buf_][c * 512]);
    }
#pragma unroll
    for (int s = 0; s < 2; ++s)
#pragma unroll
      for (int i = 0; i < 2; ++i) {
        int c = wid * 2 + i;  // 8 V chunks of 8 d-rows per sub
        gl_lds16(Vb + (size_t)(c * 8 + r8) * LL + kt_ * 128 + s * 64 + swz8,
                 &Vs[buf_][s][c * 512]);
      }
  };

  // prologue
  stage(0, 0);
  asm volatile("s_waitcnt vmcnt(0)" ::: "memory");
  __builtin_amdgcn_s_barrier();

  int buf = 0;
  for (int kt = 0; kt < LL / 128; ++kt) {
    if (kt + 1 < LL / 128) stage(kt + 1, buf ^ 1);

    const char* ksb = (const char*)&Ks[buf][0];

    // S^T - m = mfma(K, Q) with C init = -m; kf=0..7 covers 128 keys
    f32x4 sacc[2][8];
#pragma unroll
    for (int f = 0; f < 2; ++f) {
      f32x4 nm4 = {nm[f], nm[f], nm[f], nm[f]};
#pragma unroll
      for (int kf = 0; kf < 8; ++kf) sacc[f][kf] = nm4;
    }

    __builtin_amdgcn_s_setprio(1);
#pragma unroll
    for (int kf = 0; kf < 8; ++kf) {
#pragma unroll
      for (int ks = 0; ks < 2; ++ks) {
        b16x8 kfr = *(const b16x8*)(ksb + offs[kf][ks]);
#pragma unroll
        for (int f = 0; f < 2; ++f)
          sacc[f][kf] =
              __builtin_amdgcn_mfma_f32_16x16x32_bf16(kfr, qf[f][ks], sacc[f][kf], 0, 0, 0);
      }
    }
    __builtin_amdgcn_s_setprio(0);

    // ---- defer-max online softmax: sacc already holds S - m_old ----
    float lm[2];
#pragma unroll
    for (int f = 0; f < 2; ++f) {
      float mx = fmaxf(fmaxf(sacc[f][0][0], sacc[f][0][1]),
                       fmaxf(sacc[f][0][2], sacc[f][0][3]));
#pragma unroll
      for (int kf = 1; kf < 8; ++kf)
        mx = fmaxf(mx, fmaxf(fmaxf(sacc[f][kf][0], sacc[f][kf][1]),
                             fmaxf(sacc[f][kf][2], sacc[f][kf][3])));
      lm[f] = mx;
    }
    float w = fmaxf(lm[0], lm[1]);

    if (!__all(w <= 8.0f)) {
      // rare path: reduce delta across the 4 hi-lanes, rescale, shift sacc
#pragma unroll
      for (int f = 0; f < 2; ++f) {
        float mx = lm[f];
        mx = fmaxf(mx, __shfl_xor(mx, 16));
        mx = fmaxf(mx, __shfl_xor(mx, 32));
        float d = fmaxf(mx, 0.f);       // m_new = m_old + d
        float corr = __builtin_amdgcn_exp2f(-d);
        l_i[f] *= corr;
        nm[f] -= d;
#pragma unroll
        for (int db = 0; db < 4; ++db) accO[f][db] *= corr;
#pragma unroll
        for (int kf = 0; kf < 8; ++kf) sacc[f][kf] -= d;
      }
    }

    // P = exp2(sacc) packed via cvt_pk; slot c = kf>>1 (4 slots of 32 keys)
    b16x8 pfr[2][4];
#pragma unroll
    for (int f = 0; f < 2; ++f) {
      float ps = 0.f;
#pragma unroll
      for (int c = 0; c < 4; ++c) {
        float e0 = __builtin_amdgcn_exp2f(sacc[f][2 * c][0]);
        float e1 = __builtin_amdgcn_exp2f(sacc[f][2 * c][1]);
        float e2 = __builtin_amdgcn_exp2f(sacc[f][2 * c][2]);
        float e3 = __builtin_amdgcn_exp2f(sacc[f][2 * c][3]);
        float e4 = __builtin_amdgcn_exp2f(sacc[f][2 * c + 1][0]);
        float e5 = __builtin_amdgcn_exp2f(sacc[f][2 * c + 1][1]);
        float e6 = __builtin_amdgcn_exp2f(sacc[f][2 * c + 1][2]);
        float e7 = __builtin_amdgcn_exp2f(sacc[f][2 * c + 1][3]);
        ps += ((e0 + e1) + (e2 + e3)) + ((e4 + e5) + (e6 + e7));
        i32x4 pt;
        pt[0] = cvtpk(e0, e1);
        pt[1] = cvtpk(e2, e3);
        pt[2] = cvtpk(e4, e5);
        pt[3] = cvtpk(e6, e7);
        pfr[f][c] = __builtin_bit_cast(b16x8, pt);
      }
      l_i[f] += ps;
    }

    // V fragments: slot = sub*2 + ks; conflict-free b128 per sub
    b16x8 vfr[4][4];
#pragma unroll
    for (int db = 0; db < 4; ++db)
#pragma unroll
      for (int sl = 0; sl < 4; ++sl) {
        const char* vsb = (const char*)&Vs[buf][sl >> 1][0];
        vfr[db][sl] = *(const b16x8*)(vsb + offs[db][sl & 1]);
      }

    // O^T += mfma(V, P) over 4 k-slots
    __builtin_amdgcn_s_setprio(1);
#pragma unroll
    for (int f = 0; f < 2; ++f)
#pragma unroll
      for (int db = 0; db < 4; ++db)
#pragma unroll
        for (int sl = 0; sl < 4; ++sl)
          accO[f][db] = __builtin_amdgcn_mfma_f32_16x16x32_bf16(vfr[db][sl], pfr[f][sl],
                                                                accO[f][db], 0, 0, 0);
    __builtin_amdgcn_s_setprio(0);

    // next tile resident before flip
    asm volatile("s_waitcnt vmcnt(0)" ::: "memory");
    __builtin_amdgcn_s_barrier();
    buf ^= 1;
  }

  // epilogue: reduce lane-partial l across hi, O /= l, packed short4 stores
  const int bb = bh >> 4, h = bh & 15;
#pragma unroll
  for (int f = 0; f < 2; ++f) {
    float l = l_i[f];
    l += __shfl_xor(l, 16);
    l += __shfl_xor(l, 32);
    float rl = 1.0f / l;
    int q = q0 + f * 16 + lrow;
#pragma unroll
    for (int db = 0; db < 4; ++db) {
      short4 pk;
      pk.x = bfc(accO[f][db][0] * rl);
      pk.y = bfc(accO[f][db][1] * rl);
      pk.z = bfc(accO[f][db][2] * rl);
      pk.w = bfc(accO[f][db][3] * rl);
      *(short4*)(Og + (size_t)(bb * LL + q) * DD + h * 64 + db * 16 + hi * 4) = pk;
    }
  }
}

// ---------------- output GEMM: attn[4096,1024] @ WOt + bO -> f32 ----------
// 64x128 tile -> 512 blocks = 2/CU; XCD swizzle; T2 slot-swizzle on As/Bs.
__global__ __launch_bounds__(256) void out_gemm(const short* __restrict__ Ab,
                                                const short* __restrict__ Wt,
                                                const float* __restrict__ bO,
                                                float* __restrict__ Out) {
  __shared__ __align__(16) short As[64 * 32];
  __shared__ __align__(16) short Bs[128 * 32];

  const int tid = threadIdx.x;
  const int lane = tid & 63;
  const int wid = tid >> 6;
  const int orig = blockIdx.x + 8 * blockIdx.y;   // grid (8, 64)
  const int nid = (orig & 7) * 64 + (orig >> 3);  // bijective: 512 = 8*64
  const int n0 = (nid >> 6) * 128;
  const int m0 = (nid & 63) * 64;

  const int wrow = wid >> 1, wcol = wid & 1;  // wave tile: 32 rows x 64 cols
  const int lrow = lane & 15;
  const int hi = lane >> 4;
  const int sl8 = (hi ^ ((lrow >> 1) & 3)) * 8;
  const int srow = lane >> 2;
  const int scol = ((lane & 3) ^ ((lane >> 3) & 3)) * 8;

  f32x4 z4 = {0.f, 0.f, 0.f, 0.f};
  f32x4 acc[2][4];
#pragma unroll
  for (int i = 0; i < 2; ++i)
#pragma unroll
    for (int j = 0; j < 4; ++j) acc[i][j] = z4;

  for (int kt = 0; kt < DD; kt += 32) {
    gl_lds16(Ab + (size_t)(m0 + wid * 16 + srow) * DD + kt + scol, As + wid * 512);
#pragma unroll
    for (int i = 0; i < 2; ++i) {
      int c = wid * 2 + i;
      gl_lds16(Wt + (size_t)(n0 + c * 16 + srow) * DD + kt + scol, Bs + c * 512);
    }
    __syncthreads();
    b16x8 a[2], b[4];
#pragma unroll
    for (int i = 0; i < 2; ++i)
      a[i] = *(const b16x8*)(As + (wrow * 32 + i * 16 + lrow) * 32 + sl8);
#pragma unroll
    for (int j = 0; j < 4; ++j)
      b[j] = *(const b16x8*)(Bs + (wcol * 64 + j * 16 + lrow) * 32 + sl8);
#pragma unroll
    for (int i = 0; i < 2; ++i)
#pragma unroll
      for (int j = 0; j < 4; ++j)
        acc[i][j] = __builtin_amdgcn_mfma_f32_16x16x32_bf16(a[i], b[j], acc[i][j], 0, 0, 0);
    __syncthreads();
  }

  float bv[4];
#pragma unroll
  for (int j = 0; j < 4; ++j) bv[j] = bO[n0 + wcol * 64 + j * 16 + lrow];

  const int rbase = hi * 4;
#pragma unroll
  for (int i = 0; i < 2; ++i) {
    int gm = m0 + wrow * 32 + i * 16 + rbase;
#pragma unroll
    for (int j = 0; j < 4; ++j) {
      int gn = n0 + wcol * 64 + j * 16 + lrow;
#pragma unroll
      for (int r = 0; r < 4; ++r)
        Out[(size_t)(gm + r) * DD + gn] = acc[i][j][r] + bv[j];
    }
  }
}

extern "C" void kernel_launch(void* const* d_in, const int* in_sizes, int n_in,
                              void* d_out, int out_size, void* d_ws, size_t ws_size,
                              hipStream_t stream) {
  const float* X = (const float*)d_in[0];
  const float* WQ = (const float*)d_in[1];
  const float* bQ = (const float*)d_in[2];
  const float* WK = (const float*)d_in[3];
  const float* bK = (const float*)d_in[4];
  const float* WV = (const float*)d_in[5];
  const float* bV = (const float*)d_in[6];
  const float* WO = (const float*)d_in[7];
  const float* bO = (const float*)d_in[8];
  float* Out = (float*)d_out;

  // workspace layout (shorts): Xb 4M | Wt 4x1M | Q 4M | K 4M | Vt 4M | At 4M
  if (ws_size < (size_t)24 * 1024 * 1024 * 2) return;
  short* ws = (short*)d_ws;
  short* Xb = ws;
  short* Wt = Xb + (size_t)4096 * 1024;
  short* Qb = Wt + (size_t)4 * 1024 * 1024;
  short* Kb = Qb + (size_t)4096 * 1024;
  short* Vtb = Kb + (size_t)4096 * 1024;
  short* At = Vtb + (size_t)4096 * 1024;

  hipLaunchKernelGGL(prep, dim3(32, 32, 5), dim3(256), 0, stream, X, Xb, WQ, WK, WV, WO, Wt);
  hipLaunchKernelGGL(qkv_gemm, dim3(24, 32), dim3(256), 0, stream, Xb, Wt, bQ, bK, bV,
                     Qb, Kb, Vtb);
  hipLaunchKernelGGL(attn, dim3(16, 32), dim3(256), 0, stream, Qb, Kb, Vtb, At);
  hipLaunchKernelGGL(out_gemm, dim3(8, 64), dim3(256), 0, stream, At,
                     Wt + (size_t)3 * 1024 * 1024, bO, Out);
}